// Round 2
// baseline (1026.011 us; speedup 1.0000x reference)
//
#include <hip/hip_runtime.h>

// RNN: h_t = tanh(x[b,t]*W_ih + b_ih + b_hh + h_{t-1} @ W_hh^T), out = h_T @ W_out^T + b_out
// B=256 T=2048 H=256 P=24, fp32. One WG/batch (256 WGs = 256 CUs).
//
// Round-13 (resubmit; R1 bench was a GPUAcquisitionTimeout, no data):
// 1024 threads/WG (16 waves, 4 waves/SIMD) instead of 512. R12 was
// latency-bound: 23.5% occupancy (2 waves/SIMD), VALUBusy 64%, step time ~2x
// the per-SIMD FMA floor (512 cyc). The post-barrier DS-return latency,
// reduce+tanh tail, and barrier skew were exposed with only 2 streams/SIMD.
// Now each lane holds 4 rows x 16 cols = 64 weight floats (1024x64 = full
// W_hh in regs, VGPR budget ~110 < 128 cap at 16 waves/CU), 4-slot butterfly
// with masks {0,4,8,12}. Same xor-level tree (8,7,2,1) and j-ascending pk
// partials as R12 -> per-row FP sum is associatively identical -> absmax
// bit-identical. FMA issue/SIMD/step unchanged (4 waves x 32 pk); 2x the
// wave-level parallelism covers the stalls.
// Locked-in from prior rounds: select-free DPP butterfly (fused v_add_f32_dpp,
// zero cndmasks); all dup lanes write h (same-addr, free); one barrier/step;
// HSTR=20 padding; x block-prefetched one 8-step block ahead (s_load_dwordx4);
// j-outer FMA loop (FMAs start at lgkmcnt(3)).

#define BB 256
#define TT 2048
#define HH 256
#define PP 24
#define HSTR 20   // h chunk stride: 16 data + 4 pad floats

typedef float v2f __attribute__((ext_vector_type(2)));

struct alignas(16) hquad { v2f lo, hi; };   // one ds_read_b128

__device__ __forceinline__ int hidx(int k) { return (k >> 4) * HSTR + (k & 15); }

template<int CTRL>
__device__ __forceinline__ float dppadd(float dst, float src) {
    return dst + __int_as_float(__builtin_amdgcn_update_dpp(
        0, __float_as_int(src), CTRL, 0xf, 0xf, true));
}

__global__ __launch_bounds__(1024)
void rnn_persist(const float* __restrict__ x,
                 const float* __restrict__ W_ih,
                 const float* __restrict__ W_hh,
                 const float* __restrict__ b_ih,
                 const float* __restrict__ b_hh,
                 const float* __restrict__ W_out,
                 const float* __restrict__ b_out,
                 float* __restrict__ out)
{
    __shared__ __align__(16) float hbuf[2][16 * HSTR];   // 2 x 1.25 KB

    const int tid = threadIdx.x;
    const int b   = blockIdx.x;
    const int c   = tid & 15;    // K-chunk 0..15 (DPP row lane)
    const int g   = tid >> 4;    // row group 0..63 (rows 4g..4g+3)

    hbuf[0][hidx(tid & 255)] = 0.0f;   // h_0 = 0 (4-way same-addr, same value)

    // Slot->row masks for the 4-slot select-free butterfly.
    // slot s holds row 4g + ((c ^ m4[s]) >> 2). Level structure xor8 ->
    // xor7 -> xor2 -> xor1 keeps the per-row sum tree identical to R12.
    const int m4[4] = {0, 4, 8, 12};

    // Weights: 4 rows x 16 cols per lane = 64 regs.
    v2f w2[4][8];
    #pragma unroll
    for (int s = 0; s < 4; ++s) {
        const int row_idx = 4 * g + ((c ^ m4[s]) >> 2);
        const float* row = W_hh + row_idx * HH + 16 * c;
        #pragma unroll
        for (int j = 0; j < 4; ++j) {
            const float4 q = *(const float4*)(row + 4 * j);
            w2[s][2 * j + 0] = (v2f){q.x, q.y};
            w2[s][2 * j + 1] = (v2f){q.z, q.w};
        }
    }

    // Row this lane finalizes: o = 4g + (c>>2) (all 4 dup lanes agree).
    const int   o_fin = 4 * g + (c >> 2);
    const float wih   = W_ih[o_fin];
    const float cb    = b_ih[o_fin] + b_hh[o_fin];
    const int   widx  = hidx(o_fin);

    __syncthreads();

    const float* hc0 = hbuf[0] + c * HSTR;
    const float* hc1 = hbuf[1] + c * HSTR;
    const float* xb  = x + b * TT;   // uniform address stream -> s_load

    auto step = [&](const float* __restrict__ cur, float* __restrict__ nxt,
                    float xt) __attribute__((always_inline)) {
        const hquad* hq = (const hquad*)cur;
        // Issue all 4 reads back-to-back; consume in arrival order (j-outer)
        // so FMAs start at lgkmcnt(3).
        const hquad q0 = hq[0], q1 = hq[1], q2 = hq[2], q3 = hq[3];

        v2f acc[4];
        #pragma unroll
        for (int s = 0; s < 4; ++s) acc[s] = w2[s][0] * q0.lo;       // j=0
        #pragma unroll
        for (int s = 0; s < 4; ++s)
            acc[s] = __builtin_elementwise_fma(w2[s][1], q0.hi, acc[s]);
        #pragma unroll
        for (int s = 0; s < 4; ++s)
            acc[s] = __builtin_elementwise_fma(w2[s][2], q1.lo, acc[s]);
        #pragma unroll
        for (int s = 0; s < 4; ++s)
            acc[s] = __builtin_elementwise_fma(w2[s][3], q1.hi, acc[s]);
        #pragma unroll
        for (int s = 0; s < 4; ++s)
            acc[s] = __builtin_elementwise_fma(w2[s][4], q2.lo, acc[s]);
        #pragma unroll
        for (int s = 0; s < 4; ++s)
            acc[s] = __builtin_elementwise_fma(w2[s][5], q2.hi, acc[s]);
        #pragma unroll
        for (int s = 0; s < 4; ++s)
            acc[s] = __builtin_elementwise_fma(w2[s][6], q3.lo, acc[s]);
        #pragma unroll
        for (int s = 0; s < 4; ++s)
            acc[s] = __builtin_elementwise_fma(w2[s][7], q3.hi, acc[s]);

        float aa[4];
        #pragma unroll
        for (int s = 0; s < 4; ++s) aa[s] = acc[s].x + acc[s].y;

        // Select-free butterfly: 5 fused DPP adds, no cndmasks.
        // L1 xor8: slot0@c + slot2@(c^8): rows (c)>>2 == ((c^8)^8)>>2  ok
        //          slot1@c + slot3@(c^8): rows (c^4)>>2 == ((c^8)^12)>>2 ok
        float b0 = dppadd<0x128>(aa[0], aa[2]);   // xor8 (row_ror:8)
        float b1 = dppadd<0x128>(aa[1], aa[3]);
        // L2 xor7: b0@c + b1@(c^7): rows c>>2 == ((c^7)^4)>>2  ok
        float c0 = dppadd<0x141>(b0, b1);         // xor7 (row_half_mirror)
        float d  = dppadd<0x4E>(c0, c0);          // xor2 (quad_perm 2,3,0,1)
        float e  = dppadd<0xB1>(d, d);            // xor1 (quad_perm 1,0,3,2)

        // tanh(u) = 1 - 2/(e^{2u}+1); exp2 saturates cleanly at large |u|.
        const float u  = fmaf(xt, wih, cb) + e;
        const float p  = __builtin_amdgcn_exp2f(u * 2.8853900817779268f);
        const float th = fmaf(-2.f, __builtin_amdgcn_rcpf(p + 1.f), 1.f);
        nxt[widx] = th;   // all 4 dup lanes write identical value (same addr)
        __syncthreads();
    };

    // x block-prefetch: block's two float4s fetched one 8-step block ahead.
    float4 xa = *(const float4*)(xb + 0);
    float4 xc = *(const float4*)(xb + 4);
    for (int t = 0; t < TT; t += 8) {
        const int tn = (t + 8 < TT) ? (t + 8) : t;   // clamped (last block refetch)
        const float4 xa_n = *(const float4*)(xb + tn);
        const float4 xc_n = *(const float4*)(xb + tn + 4);
        step(hc0, hbuf[1], xa.x);
        step(hc1, hbuf[0], xa.y);
        step(hc0, hbuf[1], xa.z);
        step(hc1, hbuf[0], xa.w);
        step(hc0, hbuf[1], xc.x);
        step(hc1, hbuf[0], xc.y);
        step(hc0, hbuf[1], xc.z);
        step(hc1, hbuf[0], xc.w);
        xa = xa_n;
        xc = xc_n;
    }

    // Head: h_T in hbuf[0] (TT % 8 == 0). out[b,p] = b_out[p] + W_out[p,:].h_T
    if (tid < PP) {
        const float* wo = W_out + tid * HH;
        float s0 = 0.f, s1 = 0.f, s2 = 0.f, s3 = 0.f;
        #pragma unroll
        for (int h = 0; h < HH; h += 4) {
            s0 = fmaf(wo[h + 0], hbuf[0][hidx(h + 0)], s0);
            s1 = fmaf(wo[h + 1], hbuf[0][hidx(h + 1)], s1);
            s2 = fmaf(wo[h + 2], hbuf[0][hidx(h + 2)], s2);
            s3 = fmaf(wo[h + 3], hbuf[0][hidx(h + 3)], s3);
        }
        out[b * PP + tid] = b_out[tid] + (s0 + s1) + (s2 + s3);
    }
}

extern "C" void kernel_launch(void* const* d_in, const int* in_sizes, int n_in,
                              void* d_out, int out_size, void* d_ws, size_t ws_size,
                              hipStream_t stream) {
    const float* x     = (const float*)d_in[0];
    const float* W_ih  = (const float*)d_in[1];
    const float* W_hh  = (const float*)d_in[2];
    const float* b_ih  = (const float*)d_in[3];
    const float* b_hh  = (const float*)d_in[4];
    const float* W_out = (const float*)d_in[5];
    const float* b_out = (const float*)d_in[6];
    float* out = (float*)d_out;

    rnn_persist<<<BB, 1024, 0, stream>>>(x, W_ih, W_hh, b_ih, b_hh, W_out, b_out, out);
}

// Round 4
// 1013.652 us; speedup vs baseline: 1.0122x; 1.0122x over previous
//
#include <hip/hip_runtime.h>

// RNN: h_t = tanh(x[b,t]*W_ih + b_ih + b_hh + h_{t-1} @ W_hh^T), out = h_T @ W_out^T + b_out
// B=256 T=2048 H=256 P=24, fp32. One WG/batch (256 WGs = 256 CUs), 512 thr, 8 waves.
//
// Round-14 (resubmit; R3 bench was a GPUAcquisitionTimeout, no data):
// force weights into ARCH VGPRs via inline-asm v_pk_fma_f32.
// R12/R13 post-mortem: VGPR_Count (84 / 48) was far below the per-lane weight
// footprint (128 / 64 floats) -> compiler stashed W_hh rows in AGPRs and paid
// a v_accvgpr_read per weight-use. VALU-issue model with moves matches both
// measured VALUBusy (64/68.5%) AND the R12->R13 +9% regression; occupancy
// doubling didn't help because all waves are barrier-locked in the same phase
// (exposed ~390cyc/step serial chain is wave-count-invariant).
// Fix: emit all 64 pk mul/fma via asm with "v" constraints -> register
// allocator must keep w2 in VGPRs (~180 total, fits 256 cap at 2 waves/EU).
// Same j-ascending per-accumulator fma chain -> absmax bit-identical.
// Locked-in: 8-slot select-free DPP butterfly (m={0,2,7,5,8,10,15,13});
// lane finalizes row 8g+(c>>1); one barrier/step; HSTR=20 padding;
// x block-prefetched one 8-step block ahead; j-outer (FMAs start lgkmcnt(3)).

#define BB 256
#define TT 2048
#define HH 256
#define PP 24
#define HSTR 20   // h chunk stride: 16 data + 4 pad floats

typedef float v2f __attribute__((ext_vector_type(2)));

struct alignas(16) hquad { v2f lo, hi; };   // one ds_read_b128

__device__ __forceinline__ int hidx(int k) { return (k >> 4) * HSTR + (k & 15); }

template<int CTRL>
__device__ __forceinline__ float dppadd(float dst, float src) {
    return dst + __int_as_float(__builtin_amdgcn_update_dpp(
        0, __float_as_int(src), CTRL, 0xf, 0xf, true));
}

// All-"v" constraints: forces weight operands into arch VGPRs (defeats the
// compiler's AGPR-stash heuristic that was costing a move per weight-use).
#define PKMUL(a, w, q) asm("v_pk_mul_f32 %0, %1, %2" : "=v"(a) : "v"(w), "v"(q))
#define PKFMA(a, w, q) asm("v_pk_fma_f32 %0, %1, %2, %0" : "+v"(a) : "v"(w), "v"(q))

__global__ __launch_bounds__(512, 2) __attribute__((amdgpu_waves_per_eu(2, 2)))
void rnn_persist(const float* __restrict__ x,
                 const float* __restrict__ W_ih,
                 const float* __restrict__ W_hh,
                 const float* __restrict__ b_ih,
                 const float* __restrict__ b_hh,
                 const float* __restrict__ W_out,
                 const float* __restrict__ b_out,
                 float* __restrict__ out)
{
    __shared__ __align__(16) float hbuf[2][16 * HSTR];   // 2 x 1.25 KB

    const int tid = threadIdx.x;
    const int b   = blockIdx.x;
    const int c   = tid & 15;    // K-chunk 0..15 (DPP row lane)
    const int g   = tid >> 4;    // row group (rows 8g..8g+7)

    hbuf[0][hidx(tid & 255)] = 0.0f;   // h_0 = 0 (both halves write, same value)

    // Slot->row permutation for the select-free butterfly.
    const int m[8] = {0, 2, 7, 5, 8, 10, 15, 13};

    // Weights: slot s holds row 8g + ((c^m[s])>>1), cols 16c..16c+15. 128 regs.
    v2f w2[8][8];
    #pragma unroll
    for (int s = 0; s < 8; ++s) {
        const int row_idx = 8 * g + ((c ^ m[s]) >> 1);
        const float* row = W_hh + row_idx * HH + 16 * c;
        #pragma unroll
        for (int j = 0; j < 4; ++j) {
            const float4 q = *(const float4*)(row + 4 * j);
            w2[s][2 * j + 0] = (v2f){q.x, q.y};
            w2[s][2 * j + 1] = (v2f){q.z, q.w};
        }
    }

    // Row this lane finalizes: o = 8g + (c>>1) (both parities agree).
    const int   o_fin = 8 * g + (c >> 1);
    const float wih   = W_ih[o_fin];
    const float cb    = b_ih[o_fin] + b_hh[o_fin];
    const int   widx  = hidx(o_fin);

    __syncthreads();

    const float* hc0 = hbuf[0] + c * HSTR;
    const float* hc1 = hbuf[1] + c * HSTR;
    const float* xb  = x + b * TT;   // uniform address stream -> s_load

    auto step = [&](const float* __restrict__ cur, float* __restrict__ nxt,
                    float xt) __attribute__((always_inline)) {
        const hquad* hq = (const hquad*)cur;
        // Issue all 4 reads back-to-back; consume in arrival order (j-outer)
        // so FMAs start at lgkmcnt(3).
        const hquad q0 = hq[0], q1 = hq[1], q2 = hq[2], q3 = hq[3];

        v2f acc[8];
        #pragma unroll
        for (int s = 0; s < 8; ++s) PKMUL(acc[s], w2[s][0], q0.lo);   // j=0
        #pragma unroll
        for (int s = 0; s < 8; ++s) PKFMA(acc[s], w2[s][1], q0.hi);
        #pragma unroll
        for (int s = 0; s < 8; ++s) PKFMA(acc[s], w2[s][2], q1.lo);
        #pragma unroll
        for (int s = 0; s < 8; ++s) PKFMA(acc[s], w2[s][3], q1.hi);
        #pragma unroll
        for (int s = 0; s < 8; ++s) PKFMA(acc[s], w2[s][4], q2.lo);
        #pragma unroll
        for (int s = 0; s < 8; ++s) PKFMA(acc[s], w2[s][5], q2.hi);
        #pragma unroll
        for (int s = 0; s < 8; ++s) PKFMA(acc[s], w2[s][6], q3.lo);
        #pragma unroll
        for (int s = 0; s < 8; ++s) PKFMA(acc[s], w2[s][7], q3.hi);

        float aa[8];
        #pragma unroll
        for (int s = 0; s < 8; ++s) aa[s] = acc[s].x + acc[s].y;

        // Select-free butterfly: 8 fused DPP adds, no cndmasks.
        float b0 = dppadd<0x128>(aa[0], aa[4]);   // xor8 (row_ror:8)
        float b1 = dppadd<0x128>(aa[1], aa[5]);
        float b2 = dppadd<0x128>(aa[2], aa[6]);
        float b3 = dppadd<0x128>(aa[3], aa[7]);
        float c0 = dppadd<0x141>(b0, b2);         // xor7 (row_half_mirror)
        float c1 = dppadd<0x141>(b1, b3);
        float d  = dppadd<0x4E>(c0, c1);          // xor2 (quad_perm 2,3,0,1)
        float e  = dppadd<0xB1>(d, d);            // xor1 (quad_perm 1,0,3,2)

        // tanh(u) = 1 - 2/(e^{2u}+1); exp2 saturates cleanly at large |u|.
        const float u  = fmaf(xt, wih, cb) + e;
        const float p  = __builtin_amdgcn_exp2f(u * 2.8853900817779268f);
        const float th = fmaf(-2.f, __builtin_amdgcn_rcpf(p + 1.f), 1.f);
        nxt[widx] = th;   // both parities write identical value (2-way, free)
        __syncthreads();
    };

    // x block-prefetch: block's two float4s fetched one 8-step block ahead.
    float4 xa = *(const float4*)(xb + 0);
    float4 xc = *(const float4*)(xb + 4);
    for (int t = 0; t < TT; t += 8) {
        const int tn = (t + 8 < TT) ? (t + 8) : t;   // clamped (last block refetch)
        const float4 xa_n = *(const float4*)(xb + tn);
        const float4 xc_n = *(const float4*)(xb + tn + 4);
        step(hc0, hbuf[1], xa.x);
        step(hc1, hbuf[0], xa.y);
        step(hc0, hbuf[1], xa.z);
        step(hc1, hbuf[0], xa.w);
        step(hc0, hbuf[1], xc.x);
        step(hc1, hbuf[0], xc.y);
        step(hc0, hbuf[1], xc.z);
        step(hc1, hbuf[0], xc.w);
        xa = xa_n;
        xc = xc_n;
    }

    // Head: h_T in hbuf[0] (TT % 8 == 0). out[b,p] = b_out[p] + W_out[p,:].h_T
    if (tid < PP) {
        const float* wo = W_out + tid * HH;
        float s0 = 0.f, s1 = 0.f, s2 = 0.f, s3 = 0.f;
        #pragma unroll
        for (int h = 0; h < HH; h += 4) {
            s0 = fmaf(wo[h + 0], hbuf[0][hidx(h + 0)], s0);
            s1 = fmaf(wo[h + 1], hbuf[0][hidx(h + 1)], s1);
            s2 = fmaf(wo[h + 2], hbuf[0][hidx(h + 2)], s2);
            s3 = fmaf(wo[h + 3], hbuf[0][hidx(h + 3)], s3);
        }
        out[b * PP + tid] = b_out[tid] + (s0 + s1) + (s2 + s3);
    }
}

extern "C" void kernel_launch(void* const* d_in, const int* in_sizes, int n_in,
                              void* d_out, int out_size, void* d_ws, size_t ws_size,
                              hipStream_t stream) {
    const float* x     = (const float*)d_in[0];
    const float* W_ih  = (const float*)d_in[1];
    const float* W_hh  = (const float*)d_in[2];
    const float* b_ih  = (const float*)d_in[3];
    const float* b_hh  = (const float*)d_in[4];
    const float* W_out = (const float*)d_in[5];
    const float* b_out = (const float*)d_in[6];
    float* out = (float*)d_out;

    rnn_persist<<<BB, 512, 0, stream>>>(x, W_ih, W_hh, b_ih, b_hh, W_out, b_out, out);
}

// Round 5
// 967.178 us; speedup vs baseline: 1.0608x; 1.0481x over previous
//
#include <hip/hip_runtime.h>

// RNN: h_t = tanh(x[b,t]*W_ih + b_ih + b_hh + h_{t-1} @ W_hh^T), out = h_T @ W_out^T + b_out
// B=256 T=2048 H=256 P=24, fp32. One WG/batch (256 WGs = 256 CUs), 512 thr, 8 waves.
//
// Round-15: __launch_bounds__(512, 1) to kill the AGPR stash.
// Evidence chain: R12/R13/R14 all report VGPR_Count far below the per-lane
// weight footprint (84 vs ~212 demand; 48 vs ~112), and measured VALU busy
// cycles are ~2.2x the hand-counted step body (~198 vs ~88 insts/wave/step).
// => compiler splits its per-wave budget 50:50 arch/acc and stashes the w2
// array in AGPRs, paying ~110 v_accvgpr_read moves per step. The stash buys
// nothing: 212 regs -> 2 waves/SIMD on the unified gfx950 file either way.
// R14 (inline-asm "v" constraints) proved the moves can't be constrained away
// (VGPR stayed 84, busy cycles identical, scheduling worsened +7%).
// Fix: waves/EU min = 1 doubles the unified budget to 512 -> arch budget 256
// >= 212 demand -> whole w2 array lives in arch VGPRs, zero moves. Occupancy
// is unchanged (2 waves/SIMD). Same FP ops, same order -> absmax bit-identical.
// Locked-in: j-outer FMA loop (FMAs start at lgkmcnt(3)); select-free DPP
// butterfly (slot s = row (c^m[s])>>1, m={0,2,7,5,8,10,15,13}; 8 fused
// v_add_f32_dpp, zero cndmasks); lane finalizes row 8g+(c>>1); all lanes
// write h (2-way same-addr free); one barrier/step; HSTR=20 padding;
// x block-prefetched one 8-step block ahead (s_load_dwordx4).

#define BB 256
#define TT 2048
#define HH 256
#define PP 24
#define HSTR 20   // h chunk stride: 16 data + 4 pad floats

typedef float v2f __attribute__((ext_vector_type(2)));

struct alignas(16) hquad { v2f lo, hi; };   // one ds_read_b128

__device__ __forceinline__ int hidx(int k) { return (k >> 4) * HSTR + (k & 15); }

template<int CTRL>
__device__ __forceinline__ float dppadd(float dst, float src) {
    return dst + __int_as_float(__builtin_amdgcn_update_dpp(
        0, __float_as_int(src), CTRL, 0xf, 0xf, true));
}

__global__ __launch_bounds__(512, 1)
void rnn_persist(const float* __restrict__ x,
                 const float* __restrict__ W_ih,
                 const float* __restrict__ W_hh,
                 const float* __restrict__ b_ih,
                 const float* __restrict__ b_hh,
                 const float* __restrict__ W_out,
                 const float* __restrict__ b_out,
                 float* __restrict__ out)
{
    __shared__ __align__(16) float hbuf[2][16 * HSTR];   // 2 x 1.25 KB

    const int tid = threadIdx.x;
    const int b   = blockIdx.x;
    const int c   = tid & 15;    // K-chunk 0..15 (DPP row lane)
    const int g   = tid >> 4;    // row group (rows 8g..8g+7)

    hbuf[0][hidx(tid & 255)] = 0.0f;   // h_0 = 0 (both halves write, same value)

    // Slot->row permutation for the select-free butterfly.
    const int m[8] = {0, 2, 7, 5, 8, 10, 15, 13};

    // Weights: slot s holds row 8g + ((c^m[s])>>1), cols 16c..16c+15. 128 regs.
    v2f w2[8][8];
    #pragma unroll
    for (int s = 0; s < 8; ++s) {
        const int row_idx = 8 * g + ((c ^ m[s]) >> 1);
        const float* row = W_hh + row_idx * HH + 16 * c;
        #pragma unroll
        for (int j = 0; j < 4; ++j) {
            const float4 q = *(const float4*)(row + 4 * j);
            w2[s][2 * j + 0] = (v2f){q.x, q.y};
            w2[s][2 * j + 1] = (v2f){q.z, q.w};
        }
    }

    // Row this lane finalizes: o = 8g + (c>>1) (both parities agree).
    const int   o_fin = 8 * g + (c >> 1);
    const float wih   = W_ih[o_fin];
    const float cb    = b_ih[o_fin] + b_hh[o_fin];
    const int   widx  = hidx(o_fin);

    __syncthreads();

    const float* hc0 = hbuf[0] + c * HSTR;
    const float* hc1 = hbuf[1] + c * HSTR;
    const float* xb  = x + b * TT;   // uniform address stream -> s_load

    auto step = [&](const float* __restrict__ cur, float* __restrict__ nxt,
                    float xt) __attribute__((always_inline)) {
        const hquad* hq = (const hquad*)cur;
        // Issue all 4 reads back-to-back; consume in arrival order (j-outer)
        // so FMAs start at lgkmcnt(3).
        const hquad q0 = hq[0], q1 = hq[1], q2 = hq[2], q3 = hq[3];

        v2f acc[8];
        #pragma unroll
        for (int s = 0; s < 8; ++s) acc[s] = w2[s][0] * q0.lo;       // j=0
        #pragma unroll
        for (int s = 0; s < 8; ++s)
            acc[s] = __builtin_elementwise_fma(w2[s][1], q0.hi, acc[s]);
        #pragma unroll
        for (int s = 0; s < 8; ++s)
            acc[s] = __builtin_elementwise_fma(w2[s][2], q1.lo, acc[s]);
        #pragma unroll
        for (int s = 0; s < 8; ++s)
            acc[s] = __builtin_elementwise_fma(w2[s][3], q1.hi, acc[s]);
        #pragma unroll
        for (int s = 0; s < 8; ++s)
            acc[s] = __builtin_elementwise_fma(w2[s][4], q2.lo, acc[s]);
        #pragma unroll
        for (int s = 0; s < 8; ++s)
            acc[s] = __builtin_elementwise_fma(w2[s][5], q2.hi, acc[s]);
        #pragma unroll
        for (int s = 0; s < 8; ++s)
            acc[s] = __builtin_elementwise_fma(w2[s][6], q3.lo, acc[s]);
        #pragma unroll
        for (int s = 0; s < 8; ++s)
            acc[s] = __builtin_elementwise_fma(w2[s][7], q3.hi, acc[s]);

        float aa[8];
        #pragma unroll
        for (int s = 0; s < 8; ++s) aa[s] = acc[s].x + acc[s].y;

        // Select-free butterfly: 8 fused DPP adds, no cndmasks.
        float b0 = dppadd<0x128>(aa[0], aa[4]);   // xor8 (row_ror:8)
        float b1 = dppadd<0x128>(aa[1], aa[5]);
        float b2 = dppadd<0x128>(aa[2], aa[6]);
        float b3 = dppadd<0x128>(aa[3], aa[7]);
        float c0 = dppadd<0x141>(b0, b2);         // xor7 (row_half_mirror)
        float c1 = dppadd<0x141>(b1, b3);
        float d  = dppadd<0x4E>(c0, c1);          // xor2 (quad_perm 2,3,0,1)
        float e  = dppadd<0xB1>(d, d);            // xor1 (quad_perm 1,0,3,2)

        // tanh(u) = 1 - 2/(e^{2u}+1); exp2 saturates cleanly at large |u|.
        const float u  = fmaf(xt, wih, cb) + e;
        const float p  = __builtin_amdgcn_exp2f(u * 2.8853900817779268f);
        const float th = fmaf(-2.f, __builtin_amdgcn_rcpf(p + 1.f), 1.f);
        nxt[widx] = th;   // both parities write identical value (2-way, free)
        __syncthreads();
    };

    // x block-prefetch: block's two float4s fetched one 8-step block ahead.
    float4 xa = *(const float4*)(xb + 0);
    float4 xc = *(const float4*)(xb + 4);
    for (int t = 0; t < TT; t += 8) {
        const int tn = (t + 8 < TT) ? (t + 8) : t;   // clamped (last block refetch)
        const float4 xa_n = *(const float4*)(xb + tn);
        const float4 xc_n = *(const float4*)(xb + tn + 4);
        step(hc0, hbuf[1], xa.x);
        step(hc1, hbuf[0], xa.y);
        step(hc0, hbuf[1], xa.z);
        step(hc1, hbuf[0], xa.w);
        step(hc0, hbuf[1], xc.x);
        step(hc1, hbuf[0], xc.y);
        step(hc0, hbuf[1], xc.z);
        step(hc1, hbuf[0], xc.w);
        xa = xa_n;
        xc = xc_n;
    }

    // Head: h_T in hbuf[0] (TT % 8 == 0). out[b,p] = b_out[p] + W_out[p,:].h_T
    if (tid < PP) {
        const float* wo = W_out + tid * HH;
        float s0 = 0.f, s1 = 0.f, s2 = 0.f, s3 = 0.f;
        #pragma unroll
        for (int h = 0; h < HH; h += 4) {
            s0 = fmaf(wo[h + 0], hbuf[0][hidx(h + 0)], s0);
            s1 = fmaf(wo[h + 1], hbuf[0][hidx(h + 1)], s1);
            s2 = fmaf(wo[h + 2], hbuf[0][hidx(h + 2)], s2);
            s3 = fmaf(wo[h + 3], hbuf[0][hidx(h + 3)], s3);
        }
        out[b * PP + tid] = b_out[tid] + (s0 + s1) + (s2 + s3);
    }
}

extern "C" void kernel_launch(void* const* d_in, const int* in_sizes, int n_in,
                              void* d_out, int out_size, void* d_ws, size_t ws_size,
                              hipStream_t stream) {
    const float* x     = (const float*)d_in[0];
    const float* W_ih  = (const float*)d_in[1];
    const float* W_hh  = (const float*)d_in[2];
    const float* b_ih  = (const float*)d_in[3];
    const float* b_hh  = (const float*)d_in[4];
    const float* W_out = (const float*)d_in[5];
    const float* b_out = (const float*)d_in[6];
    float* out = (float*)d_out;

    rnn_persist<<<BB, 512, 0, stream>>>(x, W_ih, W_hh, b_ih, b_hh, W_out, b_out, out);
}